// Round 14
// baseline (72.591 us; speedup 1.0000x reference)
//
#include <hip/hip_runtime.h>

#define BB 32
#define HH 512
#define WW 512
#define CC 3
#define KK 16
#define NE 19          // K + 3
#define KNL 16         // nonlinear kernel terms (loaded from right_mat)
#define NN (HH * WW)   // 262144
#define BPB 16         // batches per block
#define NCOEFF (BPB * 2 * NE) // 608
// 2D output tiling: 32 wide x 8 tall per 256-thread block.
#define TLW 32
#define TLH 8
#define TILES_X (WW / TLW)  // 16
#define TILES_Y (HH / TLH)  // 64
#define NWG (TILES_X * TILES_Y * (BB / BPB)) // 2048
#define NXCD 8
#define WG_PER_XCD (NWG / NXCD) // 256

__global__ __launch_bounds__(256, 4) void tps_kernel(
    const float* __restrict__ image,        // (B,H,W,C)
    const float* __restrict__ dest_offsets, // (B, 2K)
    const float* __restrict__ right_mat,    // (NE, N)
    const float* __restrict__ L_inv,        // (NE, NE)
    const float* __restrict__ src_pts,      // (2, K)
    float* __restrict__ out)                // (B,H,W,C)
{
    // XCD-chunked bijective swizzle (NWG % 8 == 0): consecutive HW block ids
    // round-robin across XCDs, so give XCD k the contiguous logical range
    // [k*256, (k+1)*256) = one batch-group x one 128-row image band. Each
    // XCD's L2-miss stream (image band, rm band, out band) becomes long
    // sequential runs instead of interleaved fragments.
    const int lin = blockIdx.x;
    const int xcd = lin & (NXCD - 1);
    const int logical = xcd * WG_PER_XCD + (lin >> 3);
    const int bg = logical >> 10;            // batch-group 0..1
    const int w  = logical & 1023;           // tile index within group
    const int tix = w & (TILES_X - 1);
    const int tiy = w >> 4;
    const int b0 = bg * BPB;

    __shared__ float s_coeff[BPB][2][NE];
    const int tid = threadIdx.x;

    // TPS coefficients for this block's batch group:
    // coeff[bb][p][e] = sum_k (src[p][k] + off[b][p*K+k]) * L_inv[e][3+k]
    for (int i = tid; i < NCOEFF; i += 256) {
        const int bb = i / (2 * NE);
        const int rem = i - bb * (2 * NE);
        const int p = rem / NE;
        const int e = rem - p * NE;
        const int b = b0 + bb;
        float acc = 0.0f;
        #pragma unroll
        for (int k = 0; k < KK; ++k) {
            const float d = src_pts[p * KK + k] + dest_offsets[b * 2 * KK + p * KK + k];
            acc = fmaf(d, L_inv[e * NE + 3 + k], acc);
        }
        ((float*)s_coeff)[i] = acc;
    }
    __syncthreads();

    // 2D tile -> pixel: vertical y0/y1 gather reuse stays inside the block.
    const int col = tix * TLW + (tid & (TLW - 1));
    const int row = tiy * TLH + (tid >> 5);
    const int n = row * WW + col;

    // Linear right_mat rows [1; x_t; y_t]: computed (verified r5-r7, r11-r13).
    const float xt = fmaf((float)col, 2.0f / 511.0f, -1.0f);
    const float yt = fmaf((float)row, 2.0f / 511.0f, -1.0f);

    // Nonlinear rows: MUST be the exact precomputed values (r10 lesson:
    // recomputing with logf flips pixels across the trunc/clip
    // discontinuity at the image border -> absmax blowup).
    float rm[KNL];
    #pragma unroll
    for (int e = 0; e < KNL; ++e)
        rm[e] = right_mat[(size_t)(e + 3) * NN + n];

    float* __restrict__ o = out + (size_t)b0 * NN * CC + (size_t)n * CC;

    #pragma unroll
    for (int bb = 0; bb < BPB; ++bb) {
        const float* cf0 = s_coeff[bb][0];
        const float* cf1 = s_coeff[bb][1];
        float tx = fmaf(cf0[1], xt, cf0[0]);
        float ty = fmaf(cf1[1], xt, cf1[0]);
        tx = fmaf(cf0[2], yt, tx);
        ty = fmaf(cf1[2], yt, ty);
        #pragma unroll
        for (int k = 0; k < KNL; ++k) {
            tx = fmaf(cf0[3 + k], rm[k], tx);
            ty = fmaf(cf1[3 + k], rm[k], ty);
        }

        const float x = 0.5f * (tx + 1.0f) * (float)WW;
        const float y = 0.5f * (ty + 1.0f) * (float)HH;

        int x0 = (int)x;   // trunc toward zero, matches astype(int32)
        int x1 = x0 + 1;
        int y0 = (int)y;
        int y1 = y0 + 1;
        x0 = min(max(x0, 0), WW - 1);
        x1 = min(max(x1, 0), WW - 1);
        y0 = min(max(y0, 0), HH - 1);
        y1 = min(max(y1, 0), HH - 1);

        const float x0f = (float)x0, x1f = (float)x1;
        const float y0f = (float)y0, y1f = (float)y1;
        const float wa = (x1f - x) * (y1f - y);
        const float wb = (x1f - x) * (y - y0f);
        const float wc = (x - x0f) * (y1f - y);
        const float wd = (x - x0f) * (y - y0f);

        // Row-pair gather: 6 contiguous floats per row from xs = min(x0, W-2).
        const int xs = min(x0, WW - 2);
        const bool hi_a = (x0 > xs);
        const bool hi_c = (x1 > xs);

        const float* img = image + (size_t)(b0 + bb) * NN * CC;
        const float* rowA = img + ((size_t)y0 * WW + xs) * CC;
        const float* rowB = img + ((size_t)y1 * WW + xs) * CC;
        float la[6], lb[6];
        __builtin_memcpy(la, rowA, 6 * sizeof(float));
        __builtin_memcpy(lb, rowB, 6 * sizeof(float));

        float res[CC];
        #pragma unroll
        for (int c = 0; c < CC; ++c) {
            const float pa = hi_a ? la[c + 3] : la[c];
            const float pc = hi_c ? la[c + 3] : la[c];
            const float pb = hi_a ? lb[c + 3] : lb[c];
            const float pd = hi_c ? lb[c + 3] : lb[c];
            res[c] = wa * pa + wb * pb + wc * pc + wd * pd;
        }
        __builtin_memcpy(o + (size_t)bb * NN * CC, res, CC * sizeof(float));
    }
}

extern "C" void kernel_launch(void* const* d_in, const int* in_sizes, int n_in,
                              void* d_out, int out_size, void* d_ws, size_t ws_size,
                              hipStream_t stream) {
    const float* image        = (const float*)d_in[0];
    const float* dest_offsets = (const float*)d_in[1];
    const float* right_mat    = (const float*)d_in[2];
    const float* L_inv        = (const float*)d_in[3];
    const float* src_pts      = (const float*)d_in[4];
    float* out = (float*)d_out;

    hipLaunchKernelGGL(tps_kernel, dim3(NWG), dim3(256), 0, stream,
                       image, dest_offsets, right_mat, L_inv, src_pts, out);
}